// Round 1
// 132.643 us; speedup vs baseline: 1.0315x; 1.0315x over previous
//
#include <hip/hip_runtime.h>
#include <cstdint>

// Problem constants
constexpr int kN   = 4;
constexpr int kC   = 256;
constexpr int kS   = 2304;   // 48*48
constexpr int kDK  = 256;
constexpr int kDV  = 256;
constexpr int kDH  = 32;     // head dim
constexpr int kO   = 768;    // 2*DK + DV

typedef __bf16    bf16x8 __attribute__((ext_vector_type(8)));
typedef float     f32x4  __attribute__((ext_vector_type(4)));
typedef float     f32x16 __attribute__((ext_vector_type(16)));
typedef _Float16  f16;
typedef _Float16  f16x4  __attribute__((ext_vector_type(4)));
typedef _Float16  f16x8  __attribute__((ext_vector_type(8)));

union U4  { uint4 u; bf16x8 v; unsigned short s[8]; };
union F4  { float4 f; float a[4]; };
union UF8 { uint4 u; f16x8 v; f16 h[8]; };
union UF4 { uint2 u; f16x4 v; ushort4 su; };

#if __has_builtin(__builtin_amdgcn_exp2f)
#define EXP2(x) __builtin_amdgcn_exp2f(x)
#else
#define EXP2(x) exp2f(x)
#endif

__device__ inline float bf2f(unsigned short h) {
    unsigned int u = ((unsigned int)h) << 16;
    return __builtin_bit_cast(float, u);
}
__device__ inline unsigned short f2bf(float f) {
    unsigned int u = __builtin_bit_cast(unsigned int, f);
    u += 0x7fff + ((u >> 16) & 1);   // RNE
    return (unsigned short)(u >> 16);
}
__device__ inline void split2(float v, unsigned short& h, unsigned short& l) {
    h = f2bf(v);
    l = f2bf(v - bf2f(h));
}
__device__ inline unsigned int pk2(float a, float b) {
    auto p = __builtin_amdgcn_cvt_pkrtz(a, b);
    return __builtin_bit_cast(unsigned int, p);
}

// Fragment layouts:
// 16x16x32 (correctness-verified rounds 6-10):
//   A/B-frag elem (row, k): lane = ((k>>3)&3)*16 + (row&15), j = k&7
//   C-layout: D[row = (lane>>4)*4 + reg][col = lane&15].
// 32x32x16 (new attn core):
//   A-frag (row, k): lane = (k>>3)*32 + (row&31), j = k&7  (B symmetric, col=lane&31)
//   C-layout: D[row = (reg&3) + 8*(reg>>2) + 4*(lane>>5)][col = lane&31].

// ---------------------------------------------------------------------------
// prep_w (r9/r10-verified w-branch, standalone): w_qkv -> split-bf16
// B-frag wh/wl [otile 48][kt 8][lane][8]; w_proj -> f16 A-frag wp. Grid 128.
// ---------------------------------------------------------------------------
__global__ __launch_bounds__(256) void prep_w(const float* __restrict__ w_qkv,
                                              const float* __restrict__ w_proj,
                                              unsigned short* __restrict__ wh,
                                              unsigned short* __restrict__ wl,
                                              f16* __restrict__ wp) {
    int idx = blockIdx.x * 256 + threadIdx.x;
    if (idx < 24576) {           // w_qkv: 768 o x 32 c-groups
        int o = idx >> 5, cg = idx & 31;
        F4 a0, a1;
        a0.f = *(const float4*)(w_qkv + (size_t)o * kC + cg * 8);
        a1.f = *(const float4*)(w_qkv + (size_t)o * kC + cg * 8 + 4);
        U4 hv, lv;
#pragma unroll
        for (int j = 0; j < 4; j++) split2(a0.a[j], hv.s[j], lv.s[j]);
#pragma unroll
        for (int j = 0; j < 4; j++) split2(a1.a[j], hv.s[j + 4], lv.s[j + 4]);
        size_t frag = ((size_t)(o >> 4) * 8 + (cg >> 2)) * 512 + ((cg & 3) * 16 + (o & 15)) * 8;
        *(uint4*)(wh + frag) = hv.u;
        *(uint4*)(wl + frag) = lv.u;
    } else {                     // w_proj: 256 o x 32 dv-groups
        int i2 = idx - 24576;
        int o = i2 >> 5, cg = i2 & 31;
        F4 a0, a1;
        a0.f = *(const float4*)(w_proj + (size_t)o * kDV + cg * 8);
        a1.f = *(const float4*)(w_proj + (size_t)o * kDV + cg * 8 + 4);
        UF8 w;
#pragma unroll
        for (int j = 0; j < 4; j++) w.h[j] = (f16)a0.a[j];
#pragma unroll
        for (int j = 0; j < 4; j++) w.h[j + 4] = (f16)a1.a[j];
        size_t frag = ((size_t)(o >> 4) * 8 + (cg >> 2)) * 512 + ((cg & 3) * 16 + (o & 15)) * 8;
        *(uint4*)(wp + frag) = w.u;
    }
}

// ---------------------------------------------------------------------------
// gemm_qkv (fused prep_x): block (sb, oh, n) covers 64 s x 256 o where
// oh = section (0=K, 1=Q, 2=V). Stage: each block transposes+splits its own
// x strip [64 s][256 c] into LDS in A-frag order (one barrier total), then
// an LDS-resident K-loop: per ktile 8 B-frag global loads (L2-hot w) +
// 8 ds_read_b128 + 48 MFMAs (split-bf16), no further barriers.
// Grid (36, 3, 4) = 432 blocks x 256 thr; wave = 64s x 64o (4x4 frags).
// V epilogue writes the 32x32 A-frag layout with the within-16 t-row
// scramble rho'(hi,j)=8*(j>>2)+4*hi+(j&3) pre-applied (see attn_f16).
// ---------------------------------------------------------------------------
__global__ __launch_bounds__(256) void gemm_qkv(const float* __restrict__ x,
                                                const unsigned short* __restrict__ wh,
                                                const unsigned short* __restrict__ wl,
                                                const float* __restrict__ bias,
                                                f16* __restrict__ Qf,
                                                f16* __restrict__ Kf,
                                                f16* __restrict__ Vp) {
    int sb = blockIdx.x, oh = blockIdx.y, n = blockIdx.z;
    int tid  = threadIdx.x;
    int wid  = tid >> 6;
    int lane = tid & 63;
    int l15  = lane & 15;
    int quad = lane >> 4;
    int s0   = sb * 64;

    __shared__ unsigned short AH[16384];   // [kt 8][mt 4][lane 64][8]
    __shared__ unsigned short AL[16384];

    // ---- stage x strip -> split-bf16 A-frag LDS ----
    {
        int cg = tid >> 6, sl = tid & 63;
        const float* xb = x + (size_t)n * kC * kS + s0 + sl;
#pragma unroll
        for (int r = 0; r < 8; r++) {
            U4 hv, lv;
#pragma unroll
            for (int j = 0; j < 8; j++) {
                float v = xb[(size_t)(r * 32 + cg * 8 + j) * kS];
                split2(v, hv.s[j], lv.s[j]);
            }
            int off = r * 2048 + (sl >> 4) * 512 + (cg * 16 + (sl & 15)) * 8;
            *(uint4*)(&AH[off]) = hv.u;
            *(uint4*)(&AL[off]) = lv.u;
        }
    }
    __syncthreads();

    const unsigned short* bhb = wh + ((size_t)(oh * 16 + wid * 4) * 8) * 512 + (size_t)lane * 8;
    const unsigned short* blb = wl + ((size_t)(oh * 16 + wid * 4) * 8) * 512 + (size_t)lane * 8;

    f32x4 acc[4][4] = {};
#pragma unroll
    for (int kt = 0; kt < 8; kt++) {
        bf16x8 Bh[4], Bl[4];
#pragma unroll
        for (int nt = 0; nt < 4; nt++) {
            U4 u;
            u.u = *(const uint4*)(bhb + (size_t)(nt * 8 + kt) * 512); Bh[nt] = u.v;
            u.u = *(const uint4*)(blb + (size_t)(nt * 8 + kt) * 512); Bl[nt] = u.v;
        }
        bf16x8 Ah[4], Al[4];
#pragma unroll
        for (int mt = 0; mt < 4; mt++) {
            U4 u;
            u.u = *(const uint4*)(&AH[kt * 2048 + mt * 512 + lane * 8]); Ah[mt] = u.v;
            u.u = *(const uint4*)(&AL[kt * 2048 + mt * 512 + lane * 8]); Al[mt] = u.v;
        }
#pragma unroll
        for (int mt = 0; mt < 4; mt++)
#pragma unroll
            for (int nt = 0; nt < 4; nt++) {
                acc[mt][nt] = __builtin_amdgcn_mfma_f32_16x16x32_bf16(Ah[mt], Bh[nt], acc[mt][nt], 0, 0, 0);
                acc[mt][nt] = __builtin_amdgcn_mfma_f32_16x16x32_bf16(Ah[mt], Bl[nt], acc[mt][nt], 0, 0, 0);
                acc[mt][nt] = __builtin_amdgcn_mfma_f32_16x16x32_bf16(Al[mt], Bh[nt], acc[mt][nt], 0, 0, 0);
            }
    }

    // Epilogue (r7-verified): D[row=s][col=o], row = quad*4+r, col = l15.
    constexpr float kQScale = 0.0625f * 1.4426950408889634f;
#pragma unroll
    for (int nt = 0; nt < 4; nt++) {
        int col = oh * 256 + wid * 64 + nt * 16 + l15;
        float bcol = bias[col];
        int h   = (col >> 5) & 7;
        int d   = col & 31;
        int nh  = n * 8 + h;
#pragma unroll
        for (int mt = 0; mt < 4; mt++) {
            int row0 = s0 + mt * 16 + quad * 4;
            if (oh == 2) {
                // V -> 32x32 A-frag layout, t-scrambled within each 16-row tile:
                // s (within tile) = quad*4 + r ; slot lane_t = (quad&1)*32 + d,
                // j = (quad>>1)*4 + r  (inverse of rho').
                UF4 w;
#pragma unroll
                for (int r = 0; r < 4; r++) w.v[r] = (f16)(acc[mt][nt][r] + bcol);
                size_t off = (((size_t)nh * 144 + sb * 4 + mt) * 64 + (quad & 1) * 32 + d) * 8
                             + (quad >> 1) * 4;
                *(ushort4*)(Vp + off) = w.su;
            } else if (oh == 0) {
#pragma unroll
                for (int r = 0; r < 4; r++)
                    Kf[((size_t)nh * kS + row0 + r) * kDH + d] = (f16)(acc[mt][nt][r] + bcol);
            } else {
#pragma unroll
                for (int r = 0; r < 4; r++)
                    Qf[((size_t)nh * kS + row0 + r) * kDH + d] =
                        (f16)((acc[mt][nt][r] + bcol) * kQScale);
            }
        }
    }
}

// ---------------------------------------------------------------------------
// attn v7: 32x32x16_f16 core. Per 32-t body: 2 QK MFMAs (K=32 chained) +
// 2 PV MFMAs + 16 exp2 + 8 cvt_pk — 8 MFMA / 64 t vs v6's 24, VMEM 12->8.
// The P C-layout (row=(reg&3)+8g+4hi) feeds PV's B-operand with NO cross-lane
// exchange: V is stored with the matching within-16 t-row scramble
// rho'(hi,j) = 8*(j>>2)+4*hi+(j&3) (softmax+PV are t-order-invariant).
// Keeps r10 split-t structure: 3 waves/block over t-chunks, max-free softmax
// (partials exactly additive), one end-of-kernel combine barrier, ping-pong
// x2 prefetch. Grid (8 h, 72 qw, 4 n) x 192 thr; XCD head pinning (id%8==h).
// Tail over-reads land in the adjacent ws buffers (allocated, unused).
// ---------------------------------------------------------------------------
#define SUBTILE(VC, sidx, roff)                                             \
    {                                                                       \
        float e0 = EXP2(z[roff + 0]), e1 = EXP2(z[roff + 1]);               \
        float e2 = EXP2(z[roff + 2]), e3 = EXP2(z[roff + 3]);               \
        float e4 = EXP2(z[roff + 4]), e5 = EXP2(z[roff + 5]);               \
        float e6 = EXP2(z[roff + 6]), e7 = EXP2(z[roff + 7]);               \
        lsum += ((e0 + e1) + (e2 + e3)) + ((e4 + e5) + (e6 + e7));          \
        UF8 pw;                                                             \
        pw.u.x = pk2(e0, e1); pw.u.y = pk2(e2, e3);                         \
        pw.u.z = pk2(e4, e5); pw.u.w = pk2(e6, e7);                         \
        __builtin_amdgcn_s_setprio(1);                                      \
        oacc = __builtin_amdgcn_mfma_f32_32x32x16_f16(VC[sidx], pw.v,       \
                                                      oacc, 0, 0, 0);       \
        __builtin_amdgcn_s_setprio(0);                                      \
    }

#define ATTN_BODY(KC, VC, KN, VN)                                           \
    {                                                                       \
        UF8 u;                                                              \
        u.u = *(const uint4*)(kp + 1024);       KN[0] = u.v;                \
        u.u = *(const uint4*)(kp + 1040);       KN[1] = u.v;                \
        u.u = *(const uint4*)(vp + 1024);       VN[0] = u.v;                \
        u.u = *(const uint4*)(vp + 1536);       VN[1] = u.v;                \
        __builtin_amdgcn_s_setprio(1);                                      \
        f32x16 z = __builtin_amdgcn_mfma_f32_32x32x16_f16(KC[0], qf[0], zc, 0, 0, 0); \
        z = __builtin_amdgcn_mfma_f32_32x32x16_f16(KC[1], qf[1], z, 0, 0, 0); \
        __builtin_amdgcn_s_setprio(0);                                      \
        SUBTILE(VC, 0, 0)                                                   \
        SUBTILE(VC, 1, 8)                                                   \
        kp += 1024;                                                         \
        vp += 1024;                                                         \
    }

__global__ __launch_bounds__(192) void attn_f16(const f16* __restrict__ Qf,
                                                const f16* __restrict__ Kf,
                                                const f16* __restrict__ Vp,
                                                f16* __restrict__ attnF) {
    int h = blockIdx.x, qw = blockIdx.y, n = blockIdx.z;
    int nh = n * 8 + h;
    int tid  = threadIdx.x;
    int wid  = tid >> 6;           // t-chunk 0..2
    int lane = tid & 63;
    int c    = lane & 31;
    int hi   = lane >> 5;
    int sqb  = qw * 32;

    __shared__ __align__(16) float Ored[2][64][16];   // [src wave-1][lane][reg]
    __shared__ float Lred[2][32];                     // [src wave-1][col]

    // K: row-major [nh][s][32]; lane reads row (t0 + c), d-chunk hi*8 (+16 for kc=1)
    const f16* kp = Kf + (size_t)nh * kS * kDH + ((size_t)wid * 768 + c) * kDH + hi * 8;
    // V: scrambled A-frag [nh][tile 144][lane 64][8]
    const f16* vp = Vp + (size_t)nh * 144 * 512 + (size_t)wid * 48 * 512 + (size_t)lane * 8;

    f16x8 qf[2];
    {
        const f16* Qb = Qf + (size_t)nh * kS * kDH + (size_t)(sqb + c) * kDH + hi * 8;
        UF8 u;
        u.u = *(const uint4*)(Qb);      qf[0] = u.v;
        u.u = *(const uint4*)(Qb + 16); qf[1] = u.v;
    }

    f32x16 zc   = {};    // hoisted zero C-operand (no per-body zero-init movs)
    f32x16 oacc = {};    // O^T[d = (reg&3)+8*(reg>>2)+4*hi][sq = c]
    float lsum  = 0.f;

    f16x8 kA[2], kB[2], vA[2], vB[2];
    {
        UF8 u;
        u.u = *(const uint4*)(kp);        kA[0] = u.v;
        u.u = *(const uint4*)(kp + 16);   kA[1] = u.v;
        u.u = *(const uint4*)(vp);        vA[0] = u.v;
        u.u = *(const uint4*)(vp + 512);  vA[1] = u.v;
    }

    // 24 bodies of 32 t per wave, ping-pong x2 (no buffer copies)
    for (int it = 0; it < 12; it++) {
        ATTN_BODY(kA, vA, kB, vB)
        ATTN_BODY(kB, vB, kA, vA)
    }

    // each lane holds 16 of the 32 t-partials per column; lanes c and c+32
    // hold complementary halves -> single cross-half reduce
    lsum += __shfl_xor(lsum, 32);

    // cross-wave combine: waves 1,2 dump partials; wave 0 reduces + writes
    if (wid > 0) {
#pragma unroll
        for (int g = 0; g < 4; g++) {
            f32x4 t = {oacc[g * 4 + 0], oacc[g * 4 + 1], oacc[g * 4 + 2], oacc[g * 4 + 3]};
            *(f32x4*)(&Ored[wid - 1][lane][g * 4]) = t;
        }
        if (lane < 32) Lred[wid - 1][lane] = lsum;
    }
    __syncthreads();
    if (wid != 0) return;

#pragma unroll
    for (int g = 0; g < 16; g++) oacc[g] += Ored[0][lane][g] + Ored[1][lane][g];
    lsum += Lred[0][c] + Lred[1][c];

    // epilogue: normalize; write attnF in gemm_out B-frag order.
    // reg group g holds d = 8g + 4hi + r -> lane_t = g*16 + (c&15), j = 4hi + r.
    float inv = 1.0f / lsum;
    int stile = qw * 2 + (c >> 4);
    size_t base = ((size_t)(n * 144 + stile) * 8 + h) * 512 + (size_t)(c & 15) * 8 + hi * 4;
#pragma unroll
    for (int g = 0; g < 4; g++) {
        UF4 w;
#pragma unroll
        for (int r = 0; r < 4; r++) w.v[r] = (f16)(oacc[g * 4 + r] * inv);
        *(uint2*)(attnF + base + g * 128) = w.u;
    }
}

// ---------------------------------------------------------------------------
// gemm_out (r7-r10-verified): LDS-free, fragment-direct, double buffer.
// Wave computes 32o x 64s (2x4 frags), K=256 in 8 ktiles. Grid (8,36,4).
// ---------------------------------------------------------------------------
__global__ __launch_bounds__(64) void gemm_out(const f16* __restrict__ wp,
                                               const f16* __restrict__ attnF,
                                               const float* __restrict__ bias,
                                               float* __restrict__ out) {
    int ob = blockIdx.x, sb = blockIdx.y, n = blockIdx.z;
    int lane = threadIdx.x;
    int l15  = lane & 15;
    int quad = lane >> 4;

    const f16* ap = wp + ((size_t)(ob * 2) * 8) * 512 + (size_t)lane * 8;
    const f16* bp = attnF + ((size_t)(n * 144 + sb * 4) * 8) * 512 + (size_t)lane * 8;

    f16x8 af[2], bf[4], naf[2], nbf[4];
    {
        UF8 u;
#pragma unroll
        for (int i = 0; i < 2; i++) { u.u = *(const uint4*)(ap + (i * 8) * 512); af[i] = u.v; }
#pragma unroll
        for (int i = 0; i < 4; i++) { u.u = *(const uint4*)(bp + (i * 8) * 512); bf[i] = u.v; }
    }

    f32x4 acc[2][4] = {};
#pragma unroll
    for (int kt = 0; kt < 8; kt++) {
        if (kt < 7) {
            UF8 u;
#pragma unroll
            for (int i = 0; i < 2; i++) { u.u = *(const uint4*)(ap + (i * 8 + kt + 1) * 512); naf[i] = u.v; }
#pragma unroll
            for (int i = 0; i < 4; i++) { u.u = *(const uint4*)(bp + (i * 8 + kt + 1) * 512); nbf[i] = u.v; }
        }
#pragma unroll
        for (int mt = 0; mt < 2; mt++)
#pragma unroll
            for (int nt = 0; nt < 4; nt++)
                acc[mt][nt] = __builtin_amdgcn_mfma_f32_16x16x32_f16(af[mt], bf[nt],
                                                                     acc[mt][nt], 0, 0, 0);
#pragma unroll
        for (int i = 0; i < 2; i++) af[i] = naf[i];
#pragma unroll
        for (int i = 0; i < 4; i++) bf[i] = nbf[i];
    }

#pragma unroll
    for (int mt = 0; mt < 2; mt++) {
        int row0 = ob * 32 + mt * 16 + quad * 4;   // o
#pragma unroll
        for (int nt = 0; nt < 4; nt++) {
            int col = sb * 64 + nt * 16 + l15;     // s
#pragma unroll
            for (int r = 0; r < 4; r++)
                out[((size_t)n * kDV + row0 + r) * kS + col] = acc[mt][nt][r] + bias[row0 + r];
        }
    }
}

// ---------------------------------------------------------------------------
extern "C" void kernel_launch(void* const* d_in, const int* in_sizes, int n_in,
                              void* d_out, int out_size, void* d_ws, size_t ws_size,
                              hipStream_t stream) {
    const float* x      = (const float*)d_in[0];
    const float* w_qkv  = (const float*)d_in[1];
    const float* b_qkv  = (const float*)d_in[2];
    const float* w_proj = (const float*)d_in[3];
    const float* b_proj = (const float*)d_in[4];
    float* out = (float*)d_out;

    constexpr size_t kXE = (size_t)kN * kS * kC;     // 2,359,296
    unsigned short* wh = (unsigned short*)d_ws;      // w_qkv B-frag hi
    unsigned short* wl = wh + 196608;
    f16* wpF   = (f16*)(wl + 196608);                // w_proj A-frag f16
    f16* Qf    = wpF + 65536;                        // [32 nh][2304][32]
    f16* Kf    = Qf + kXE;
    f16* Vp    = Kf + kXE;                           // [32 nh][144][64][8] scrambled A-frag
    f16* attnF = Vp + kXE;                           // B-frag [n][144][8][512]

    prep_w<<<dim3(128), 256, 0, stream>>>(w_qkv, w_proj, wh, wl, wpF);

    gemm_qkv<<<dim3(36, 3, 4), 256, 0, stream>>>(x, wh, wl, b_qkv, Qf, Kf, Vp);

    attn_f16<<<dim3(8, 72, 4), 192, 0, stream>>>(Qf, Kf, Vp, attnF);

    gemm_out<<<dim3(8, 36, 4), 64, 0, stream>>>(wpF, attnF, b_proj, out);
}

// Round 2
// 128.671 us; speedup vs baseline: 1.0634x; 1.0309x over previous
//
#include <hip/hip_runtime.h>
#include <cstdint>

// Problem constants
constexpr int kN   = 4;
constexpr int kC   = 256;
constexpr int kS   = 2304;   // 48*48
constexpr int kDK  = 256;
constexpr int kDV  = 256;
constexpr int kDH  = 32;     // head dim
constexpr int kO   = 768;    // 2*DK + DV

typedef __bf16    bf16x8 __attribute__((ext_vector_type(8)));
typedef float     f32x4  __attribute__((ext_vector_type(4)));
typedef float     f32x16 __attribute__((ext_vector_type(16)));
typedef _Float16  f16;
typedef _Float16  f16x2  __attribute__((ext_vector_type(2)));
typedef _Float16  f16x4  __attribute__((ext_vector_type(4)));
typedef _Float16  f16x8  __attribute__((ext_vector_type(8)));

union U4  { uint4 u; bf16x8 v; unsigned short s[8]; };
union F4  { float4 f; float a[4]; };
union UF8 { uint4 u; f16x8 v; f16 h[8]; };
union UF4 { uint2 u; f16x4 v; ushort4 su; };

#if __has_builtin(__builtin_amdgcn_exp2f)
#define EXP2(x) __builtin_amdgcn_exp2f(x)
#else
#define EXP2(x) exp2f(x)
#endif

__device__ inline float bf2f(unsigned short h) {
    unsigned int u = ((unsigned int)h) << 16;
    return __builtin_bit_cast(float, u);
}
__device__ inline unsigned short f2bf(float f) {
    unsigned int u = __builtin_bit_cast(unsigned int, f);
    u += 0x7fff + ((u >> 16) & 1);   // RNE
    return (unsigned short)(u >> 16);
}
__device__ inline void split2(float v, unsigned short& h, unsigned short& l) {
    h = f2bf(v);
    l = f2bf(v - bf2f(h));
}
__device__ inline unsigned int pk2(float a, float b) {
    auto p = __builtin_amdgcn_cvt_pkrtz(a, b);
    return __builtin_bit_cast(unsigned int, p);
}

// Fragment layouts:
// 16x16x32 (correctness-verified rounds 6-10):
//   A/B-frag elem (row, k): lane = ((k>>3)&3)*16 + (row&15), j = k&7
//   C-layout: D[row = (lane>>4)*4 + reg][col = lane&15].
// 32x32x16 (attn core, r1-verified):
//   A-frag (row, k): lane = (k>>3)*32 + (row&31), j = k&7  (B symmetric, col=lane&31)
//   C-layout: D[row = (reg&3) + 8*(reg>>2) + 4*(lane>>5)][col = lane&31].

// ---------------------------------------------------------------------------
// prep_w (r9/r10-verified w-branch, standalone): w_qkv -> split-bf16
// B-frag wh/wl [otile 48][kt 8][lane][8]; w_proj -> f16 A-frag wp. Grid 128.
// ---------------------------------------------------------------------------
__global__ __launch_bounds__(256) void prep_w(const float* __restrict__ w_qkv,
                                              const float* __restrict__ w_proj,
                                              unsigned short* __restrict__ wh,
                                              unsigned short* __restrict__ wl,
                                              f16* __restrict__ wp) {
    int idx = blockIdx.x * 256 + threadIdx.x;
    if (idx < 24576) {           // w_qkv: 768 o x 32 c-groups
        int o = idx >> 5, cg = idx & 31;
        F4 a0, a1;
        a0.f = *(const float4*)(w_qkv + (size_t)o * kC + cg * 8);
        a1.f = *(const float4*)(w_qkv + (size_t)o * kC + cg * 8 + 4);
        U4 hv, lv;
#pragma unroll
        for (int j = 0; j < 4; j++) split2(a0.a[j], hv.s[j], lv.s[j]);
#pragma unroll
        for (int j = 0; j < 4; j++) split2(a1.a[j], hv.s[j + 4], lv.s[j + 4]);
        size_t frag = ((size_t)(o >> 4) * 8 + (cg >> 2)) * 512 + ((cg & 3) * 16 + (o & 15)) * 8;
        *(uint4*)(wh + frag) = hv.u;
        *(uint4*)(wl + frag) = lv.u;
    } else {                     // w_proj: 256 o x 32 dv-groups
        int i2 = idx - 24576;
        int o = i2 >> 5, cg = i2 & 31;
        F4 a0, a1;
        a0.f = *(const float4*)(w_proj + (size_t)o * kDV + cg * 8);
        a1.f = *(const float4*)(w_proj + (size_t)o * kDV + cg * 8 + 4);
        UF8 w;
#pragma unroll
        for (int j = 0; j < 4; j++) w.h[j] = (f16)a0.a[j];
#pragma unroll
        for (int j = 0; j < 4; j++) w.h[j + 4] = (f16)a1.a[j];
        size_t frag = ((size_t)(o >> 4) * 8 + (cg >> 2)) * 512 + ((cg & 3) * 16 + (o & 15)) * 8;
        *(uint4*)(wp + frag) = w.u;
    }
}

// ---------------------------------------------------------------------------
// gemm_qkv v2: s-tile 64 -> 32 for 2x block parallelism (432 -> 864 blocks;
// the old grid was 1.7 blocks/CU = 6.75 waves/CU, latency-exposed).
// Block (sb, oh, n) covers 32 s x 256 o, oh = section (0=K, 1=Q, 2=V).
// Stage: transpose+split x strip [32 s][256 c] into LDS A-frag order (one
// barrier), then LDS-resident K-loop: per ktile 8 B-frag global loads
// (L2-hot w) + 4 ds_read_b128 + 24 MFMAs (split-bf16). Per-wave acc halves
// to 2x4 frags (32 VGPRs); LDS halves to 32 KB.
// Grid (72, 3, 4) = 864 blocks x 256 thr; wave = 32s x 64o.
// ---------------------------------------------------------------------------
__global__ __launch_bounds__(256) void gemm_qkv(const float* __restrict__ x,
                                                const unsigned short* __restrict__ wh,
                                                const unsigned short* __restrict__ wl,
                                                const float* __restrict__ bias,
                                                f16* __restrict__ Qf,
                                                f16* __restrict__ Kf,
                                                f16* __restrict__ Vp) {
    int sb = blockIdx.x, oh = blockIdx.y, n = blockIdx.z;
    int tid  = threadIdx.x;
    int wid  = tid >> 6;
    int lane = tid & 63;
    int l15  = lane & 15;
    int quad = lane >> 4;
    int s0   = sb * 32;

    __shared__ unsigned short AH[8192];   // [kt 8][mt 2][lane 64][8]
    __shared__ unsigned short AL[8192];

    // ---- stage x strip -> split-bf16 A-frag LDS ----
    {
        int cg = tid >> 5;          // 0..7 (c-group of 8 within 64-chunk pair)
        int sl = tid & 31;          // s within strip
        const float* xb = x + (size_t)n * kC * kS + s0 + sl;
#pragma unroll
        for (int r = 0; r < 4; r++) {
            U4 hv, lv;
#pragma unroll
            for (int j = 0; j < 8; j++) {
                float v = xb[(size_t)(r * 64 + cg * 8 + j) * kS];
                split2(v, hv.s[j], lv.s[j]);
            }
            // c = r*64 + cg*8 + j: kt = r*2 + (cg>>2); lane-part ((cg&3)*16 + s&15)
            int off = (r * 2 + (cg >> 2)) * 1024 + (sl >> 4) * 512 + ((cg & 3) * 16 + (sl & 15)) * 8;
            *(uint4*)(&AH[off]) = hv.u;
            *(uint4*)(&AL[off]) = lv.u;
        }
    }
    __syncthreads();

    const unsigned short* bhb = wh + ((size_t)(oh * 16 + wid * 4) * 8) * 512 + (size_t)lane * 8;
    const unsigned short* blb = wl + ((size_t)(oh * 16 + wid * 4) * 8) * 512 + (size_t)lane * 8;

    f32x4 acc[2][4] = {};
#pragma unroll
    for (int kt = 0; kt < 8; kt++) {
        bf16x8 Bh[4], Bl[4];
#pragma unroll
        for (int nt = 0; nt < 4; nt++) {
            U4 u;
            u.u = *(const uint4*)(bhb + (size_t)(nt * 8 + kt) * 512); Bh[nt] = u.v;
            u.u = *(const uint4*)(blb + (size_t)(nt * 8 + kt) * 512); Bl[nt] = u.v;
        }
        bf16x8 Ah[2], Al[2];
#pragma unroll
        for (int mt = 0; mt < 2; mt++) {
            U4 u;
            u.u = *(const uint4*)(&AH[kt * 1024 + mt * 512 + lane * 8]); Ah[mt] = u.v;
            u.u = *(const uint4*)(&AL[kt * 1024 + mt * 512 + lane * 8]); Al[mt] = u.v;
        }
#pragma unroll
        for (int mt = 0; mt < 2; mt++)
#pragma unroll
            for (int nt = 0; nt < 4; nt++) {
                acc[mt][nt] = __builtin_amdgcn_mfma_f32_16x16x32_bf16(Ah[mt], Bh[nt], acc[mt][nt], 0, 0, 0);
                acc[mt][nt] = __builtin_amdgcn_mfma_f32_16x16x32_bf16(Ah[mt], Bl[nt], acc[mt][nt], 0, 0, 0);
                acc[mt][nt] = __builtin_amdgcn_mfma_f32_16x16x32_bf16(Al[mt], Bh[nt], acc[mt][nt], 0, 0, 0);
            }
    }

    // Epilogue (r7-verified): D[row=s][col=o], row = quad*4+r, col = l15.
    constexpr float kQScale = 0.0625f * 1.4426950408889634f;
#pragma unroll
    for (int nt = 0; nt < 4; nt++) {
        int col = oh * 256 + wid * 64 + nt * 16 + l15;
        float bcol = bias[col];
        int h   = (col >> 5) & 7;
        int d   = col & 31;
        int nh  = n * 8 + h;
#pragma unroll
        for (int mt = 0; mt < 2; mt++) {
            int row0 = s0 + mt * 16 + quad * 4;
            if (oh == 2) {
                // V -> 32x32 A-frag layout, t-scrambled within each 16-row tile:
                // slot lane_t = (quad&1)*32 + d, j = (quad>>1)*4 + r (inverse of rho').
                UF4 w;
#pragma unroll
                for (int r = 0; r < 4; r++) w.v[r] = (f16)(acc[mt][nt][r] + bcol);
                size_t off = (((size_t)nh * 144 + sb * 2 + mt) * 64 + (quad & 1) * 32 + d) * 8
                             + (quad >> 1) * 4;
                *(ushort4*)(Vp + off) = w.su;
            } else if (oh == 0) {
#pragma unroll
                for (int r = 0; r < 4; r++)
                    Kf[((size_t)nh * kS + row0 + r) * kDH + d] = (f16)(acc[mt][nt][r] + bcol);
            } else {
#pragma unroll
                for (int r = 0; r < 4; r++)
                    Qf[((size_t)nh * kS + row0 + r) * kDH + d] =
                        (f16)((acc[mt][nt][r] + bcol) * kQScale);
            }
        }
    }
}

// ---------------------------------------------------------------------------
// attn v8: v7 32x32x16 core + occupancy fix. launch_bounds(192, 4) caps
// combined VGPR+AGPR at 128 (v7 measured 27% occupancy = the 8-wave/CU reg
// step for combined regs in (128,256]; hand count of the loop is ~116).
// lsum via v_dot2_f32_f16 on the already-packed f16 P pairs (8 dot2 replace
// 16 VALU adds; two accumulators halve the chain; denominator now sums the
// same f16-rounded P used in the numerator). Ored combine column-swizzled
// (g ^ ((lane>>1)&3)) to kill the 663K bank-conflict cycles of the [lane][16]
// layout. Grid (8 h, 72 qw, 4 n) x 192 thr; XCD head pinning (id%8==h).
// ---------------------------------------------------------------------------
#if __has_builtin(__builtin_amdgcn_fdot2)
#define LADD(acc, lou, hiu)                                                 \
    acc = __builtin_amdgcn_fdot2(__builtin_bit_cast(f16x2, lou), one2, acc, false); \
    acc = __builtin_amdgcn_fdot2(__builtin_bit_cast(f16x2, hiu), one2, acc, false);
#else
#define LADD(acc, lou, hiu)                                                 \
    {                                                                       \
        UF4 t; t.u.x = lou; t.u.y = hiu;                                    \
        acc += (float)t.v[0] + (float)t.v[1] + (float)t.v[2] + (float)t.v[3]; \
    }
#endif

#define SUBTILE(VC, sidx, roff, lacc)                                       \
    {                                                                       \
        float e0 = EXP2(z[roff + 0]), e1 = EXP2(z[roff + 1]);               \
        float e2 = EXP2(z[roff + 2]), e3 = EXP2(z[roff + 3]);               \
        float e4 = EXP2(z[roff + 4]), e5 = EXP2(z[roff + 5]);               \
        float e6 = EXP2(z[roff + 6]), e7 = EXP2(z[roff + 7]);               \
        UF8 pw;                                                             \
        pw.u.x = pk2(e0, e1); pw.u.y = pk2(e2, e3);                         \
        pw.u.z = pk2(e4, e5); pw.u.w = pk2(e6, e7);                         \
        LADD(lacc, pw.u.x, pw.u.y)                                          \
        LADD(lacc, pw.u.z, pw.u.w)                                          \
        __builtin_amdgcn_s_setprio(1);                                      \
        oacc = __builtin_amdgcn_mfma_f32_32x32x16_f16(VC[sidx], pw.v,       \
                                                      oacc, 0, 0, 0);       \
        __builtin_amdgcn_s_setprio(0);                                      \
    }

#define ATTN_BODY(KC, VC, KN, VN)                                           \
    {                                                                       \
        UF8 u;                                                              \
        u.u = *(const uint4*)(kp + 1024);       KN[0] = u.v;                \
        u.u = *(const uint4*)(kp + 1040);       KN[1] = u.v;                \
        u.u = *(const uint4*)(vp + 1024);       VN[0] = u.v;                \
        u.u = *(const uint4*)(vp + 1536);       VN[1] = u.v;                \
        __builtin_amdgcn_s_setprio(1);                                      \
        f32x16 z = __builtin_amdgcn_mfma_f32_32x32x16_f16(KC[0], qf[0], zc, 0, 0, 0); \
        z = __builtin_amdgcn_mfma_f32_32x32x16_f16(KC[1], qf[1], z, 0, 0, 0); \
        __builtin_amdgcn_s_setprio(0);                                      \
        SUBTILE(VC, 0, 0, lsumA)                                            \
        SUBTILE(VC, 1, 8, lsumB)                                            \
        kp += 1024;                                                         \
        vp += 1024;                                                         \
    }

__global__ __launch_bounds__(192, 4) void attn_f16(const f16* __restrict__ Qf,
                                                   const f16* __restrict__ Kf,
                                                   const f16* __restrict__ Vp,
                                                   f16* __restrict__ attnF) {
    int h = blockIdx.x, qw = blockIdx.y, n = blockIdx.z;
    int nh = n * 8 + h;
    int tid  = threadIdx.x;
    int wid  = tid >> 6;           // t-chunk 0..2
    int lane = tid & 63;
    int c    = lane & 31;
    int hi   = lane >> 5;
    int sqb  = qw * 32;

    __shared__ __align__(16) float Ored[2][64][16];   // [src wave-1][lane][reg, col-swizzled]
    __shared__ float Lred[2][32];                     // [src wave-1][col]

    // K: row-major [nh][s][32]; lane reads row (t0 + c), d-chunk hi*8 (+16 for kc=1)
    const f16* kp = Kf + (size_t)nh * kS * kDH + ((size_t)wid * 768 + c) * kDH + hi * 8;
    // V: scrambled A-frag [nh][tile 144][lane 64][8]
    const f16* vp = Vp + (size_t)nh * 144 * 512 + (size_t)wid * 48 * 512 + (size_t)lane * 8;

    f16x8 qf[2];
    {
        const f16* Qb = Qf + (size_t)nh * kS * kDH + (size_t)(sqb + c) * kDH + hi * 8;
        UF8 u;
        u.u = *(const uint4*)(Qb);      qf[0] = u.v;
        u.u = *(const uint4*)(Qb + 16); qf[1] = u.v;
    }

    f32x16 zc   = {};    // hoisted zero C-operand
    f32x16 oacc = {};    // O^T[d = (reg&3)+8*(reg>>2)+4*hi][sq = c]
    float lsumA = 0.f, lsumB = 0.f;
    const f16x2 one2 = {(_Float16)1.0f, (_Float16)1.0f};

    f16x8 kA[2], kB[2], vA[2], vB[2];
    {
        UF8 u;
        u.u = *(const uint4*)(kp);        kA[0] = u.v;
        u.u = *(const uint4*)(kp + 16);   kA[1] = u.v;
        u.u = *(const uint4*)(vp);        vA[0] = u.v;
        u.u = *(const uint4*)(vp + 512);  vA[1] = u.v;
    }

    // 24 bodies of 32 t per wave, ping-pong x2 (no buffer copies); tail
    // over-reads land in the adjacent ws buffers (allocated, values unused).
    for (int it = 0; it < 12; it++) {
        ATTN_BODY(kA, vA, kB, vB)
        ATTN_BODY(kB, vB, kA, vA)
    }

    float lsum = lsumA + lsumB;
    // lanes c and c+32 hold complementary t-halves -> single cross-half reduce
    lsum += __shfl_xor(lsum, 32);

    // cross-wave combine: waves 1,2 dump partials; wave 0 reduces + writes.
    // Column slot swizzled by g ^ ((lane>>1)&3): spreads the 16B stores of a
    // wave across all 32 banks (plain [lane][16] puts all even lanes on one
    // 4-bank group -> the 663K conflict cycles seen in r1).
    int gsw = (lane >> 1) & 3;
    if (wid > 0) {
#pragma unroll
        for (int g = 0; g < 4; g++) {
            f32x4 t = {oacc[g * 4 + 0], oacc[g * 4 + 1], oacc[g * 4 + 2], oacc[g * 4 + 3]};
            *(f32x4*)(&Ored[wid - 1][lane][(g ^ gsw) * 4]) = t;
        }
        if (lane < 32) Lred[wid - 1][lane] = lsum;
    }
    __syncthreads();
    if (wid != 0) return;

#pragma unroll
    for (int g = 0; g < 4; g++) {
        f32x4 a = *(const f32x4*)(&Ored[0][lane][(g ^ gsw) * 4]);
        f32x4 b = *(const f32x4*)(&Ored[1][lane][(g ^ gsw) * 4]);
#pragma unroll
        for (int r = 0; r < 4; r++) oacc[g * 4 + r] += a[r] + b[r];
    }
    lsum += Lred[0][c] + Lred[1][c];

    // epilogue: normalize; write attnF in gemm_out B-frag order.
    // reg group g holds d = 8g + 4hi + r -> lane_t = g*16 + (c&15), j = 4hi + r.
    float inv = 1.0f / lsum;
    int stile = qw * 2 + (c >> 4);
    size_t base = ((size_t)(n * 144 + stile) * 8 + h) * 512 + (size_t)(c & 15) * 8 + hi * 4;
#pragma unroll
    for (int g = 0; g < 4; g++) {
        UF4 w;
#pragma unroll
        for (int r = 0; r < 4; r++) w.v[r] = (f16)(oacc[g * 4 + r] * inv);
        *(uint2*)(attnF + base + g * 128) = w.u;
    }
}

// ---------------------------------------------------------------------------
// gemm_out (r7-r10-verified): LDS-free, fragment-direct, double buffer.
// Wave computes 32o x 64s (2x4 frags), K=256 in 8 ktiles. Grid (8,36,4).
// ---------------------------------------------------------------------------
__global__ __launch_bounds__(64) void gemm_out(const f16* __restrict__ wp,
                                               const f16* __restrict__ attnF,
                                               const float* __restrict__ bias,
                                               float* __restrict__ out) {
    int ob = blockIdx.x, sb = blockIdx.y, n = blockIdx.z;
    int lane = threadIdx.x;
    int l15  = lane & 15;
    int quad = lane >> 4;

    const f16* ap = wp + ((size_t)(ob * 2) * 8) * 512 + (size_t)lane * 8;
    const f16* bp = attnF + ((size_t)(n * 144 + sb * 4) * 8) * 512 + (size_t)lane * 8;

    f16x8 af[2], bf[4], naf[2], nbf[4];
    {
        UF8 u;
#pragma unroll
        for (int i = 0; i < 2; i++) { u.u = *(const uint4*)(ap + (i * 8) * 512); af[i] = u.v; }
#pragma unroll
        for (int i = 0; i < 4; i++) { u.u = *(const uint4*)(bp + (i * 8) * 512); bf[i] = u.v; }
    }

    f32x4 acc[2][4] = {};
#pragma unroll
    for (int kt = 0; kt < 8; kt++) {
        if (kt < 7) {
            UF8 u;
#pragma unroll
            for (int i = 0; i < 2; i++) { u.u = *(const uint4*)(ap + (i * 8 + kt + 1) * 512); naf[i] = u.v; }
#pragma unroll
            for (int i = 0; i < 4; i++) { u.u = *(const uint4*)(bp + (i * 8 + kt + 1) * 512); nbf[i] = u.v; }
        }
#pragma unroll
        for (int mt = 0; mt < 2; mt++)
#pragma unroll
            for (int nt = 0; nt < 4; nt++)
                acc[mt][nt] = __builtin_amdgcn_mfma_f32_16x16x32_f16(af[mt], bf[nt],
                                                                     acc[mt][nt], 0, 0, 0);
#pragma unroll
        for (int i = 0; i < 2; i++) af[i] = naf[i];
#pragma unroll
        for (int i = 0; i < 4; i++) bf[i] = nbf[i];
    }

#pragma unroll
    for (int mt = 0; mt < 2; mt++) {
        int row0 = ob * 32 + mt * 16 + quad * 4;   // o
#pragma unroll
        for (int nt = 0; nt < 4; nt++) {
            int col = sb * 64 + nt * 16 + l15;     // s
#pragma unroll
            for (int r = 0; r < 4; r++)
                out[((size_t)n * kDV + row0 + r) * kS + col] = acc[mt][nt][r] + bias[row0 + r];
        }
    }
}

// ---------------------------------------------------------------------------
extern "C" void kernel_launch(void* const* d_in, const int* in_sizes, int n_in,
                              void* d_out, int out_size, void* d_ws, size_t ws_size,
                              hipStream_t stream) {
    const float* x      = (const float*)d_in[0];
    const float* w_qkv  = (const float*)d_in[1];
    const float* b_qkv  = (const float*)d_in[2];
    const float* w_proj = (const float*)d_in[3];
    const float* b_proj = (const float*)d_in[4];
    float* out = (float*)d_out;

    constexpr size_t kXE = (size_t)kN * kS * kC;     // 2,359,296
    unsigned short* wh = (unsigned short*)d_ws;      // w_qkv B-frag hi
    unsigned short* wl = wh + 196608;
    f16* wpF   = (f16*)(wl + 196608);                // w_proj A-frag f16
    f16* Qf    = wpF + 65536;                        // [32 nh][2304][32]
    f16* Kf    = Qf + kXE;
    f16* Vp    = Kf + kXE;                           // [32 nh][144][64][8] scrambled A-frag
    f16* attnF = Vp + kXE;                           // B-frag [n][144][8][512]

    prep_w<<<dim3(128), 256, 0, stream>>>(w_qkv, w_proj, wh, wl, wpF);

    gemm_qkv<<<dim3(72, 3, 4), 256, 0, stream>>>(x, wh, wl, b_qkv, Qf, Kf, Vp);

    attn_f16<<<dim3(8, 72, 4), 192, 0, stream>>>(Qf, Kf, Vp, attnF);

    gemm_out<<<dim3(8, 36, 4), 64, 0, stream>>>(wpF, attnF, b_proj, out);
}

// Round 3
// 121.979 us; speedup vs baseline: 1.1217x; 1.0549x over previous
//
#include <hip/hip_runtime.h>
#include <cstdint>

// Problem constants
constexpr int kN   = 4;
constexpr int kC   = 256;
constexpr int kS   = 2304;   // 48*48
constexpr int kDK  = 256;
constexpr int kDV  = 256;
constexpr int kDH  = 32;     // head dim
constexpr int kO   = 768;    // 2*DK + DV

typedef __bf16    bf16x8 __attribute__((ext_vector_type(8)));
typedef float     f32x4  __attribute__((ext_vector_type(4)));
typedef float     f32x16 __attribute__((ext_vector_type(16)));
typedef _Float16  f16;
typedef _Float16  f16x2  __attribute__((ext_vector_type(2)));
typedef _Float16  f16x4  __attribute__((ext_vector_type(4)));
typedef _Float16  f16x8  __attribute__((ext_vector_type(8)));

union U4  { uint4 u; bf16x8 v; unsigned short s[8]; };
union F4  { float4 f; float a[4]; };
union UF8 { uint4 u; f16x8 v; f16 h[8]; };
union UF4 { uint2 u; f16x4 v; ushort4 su; };

#if __has_builtin(__builtin_amdgcn_exp2f)
#define EXP2(x) __builtin_amdgcn_exp2f(x)
#else
#define EXP2(x) exp2f(x)
#endif

__device__ inline unsigned int pk2(float a, float b) {
    auto p = __builtin_amdgcn_cvt_pkrtz(a, b);
    return __builtin_bit_cast(unsigned int, p);
}
// f16 hi/lo split: h captures 11 mantissa bits, l the next 11 (~22-bit exact).
__device__ inline void split2f(float v, f16& h, f16& l) {
    h = (f16)v;
    l = (f16)(v - (float)h);
}

// Fragment layouts:
// 16x16x32 (correctness-verified rounds 6-10; dtype-independent):
//   A/B-frag elem (row, k): lane = ((k>>3)&3)*16 + (row&15), j = k&7
//   C-layout: D[row = (lane>>4)*4 + reg][col = lane&15].
// 32x32x16 (attn core, r1-verified):
//   A-frag (row, k): lane = (k>>3)*32 + (row&31), j = k&7  (B symmetric, col=lane&31)
//   C-layout: D[row = (reg&3) + 8*(reg>>2) + 4*(lane>>5)][col = lane&31].

// ---------------------------------------------------------------------------
// prep_w v2: w_qkv -> SPLIT-F16 B-frags wh/wl [otile 48][kt 8][lane][8]
// (w exact to ~22 bits; x side will be single f16 -> 2-MFMA scheme).
// w_proj -> f16 A-frag wp. Grid 128.
// ---------------------------------------------------------------------------
__global__ __launch_bounds__(256) void prep_w(const float* __restrict__ w_qkv,
                                              const float* __restrict__ w_proj,
                                              unsigned short* __restrict__ wh,
                                              unsigned short* __restrict__ wl,
                                              f16* __restrict__ wp) {
    int idx = blockIdx.x * 256 + threadIdx.x;
    if (idx < 24576) {           // w_qkv: 768 o x 32 c-groups
        int o = idx >> 5, cg = idx & 31;
        F4 a0, a1;
        a0.f = *(const float4*)(w_qkv + (size_t)o * kC + cg * 8);
        a1.f = *(const float4*)(w_qkv + (size_t)o * kC + cg * 8 + 4);
        UF8 hv, lv;
#pragma unroll
        for (int j = 0; j < 4; j++) split2f(a0.a[j], hv.h[j], lv.h[j]);
#pragma unroll
        for (int j = 0; j < 4; j++) split2f(a1.a[j], hv.h[j + 4], lv.h[j + 4]);
        size_t frag = ((size_t)(o >> 4) * 8 + (cg >> 2)) * 512 + ((cg & 3) * 16 + (o & 15)) * 8;
        *(uint4*)(wh + frag) = hv.u;
        *(uint4*)(wl + frag) = lv.u;
    } else {                     // w_proj: 256 o x 32 dv-groups
        int i2 = idx - 24576;
        int o = i2 >> 5, cg = i2 & 31;
        F4 a0, a1;
        a0.f = *(const float4*)(w_proj + (size_t)o * kDV + cg * 8);
        a1.f = *(const float4*)(w_proj + (size_t)o * kDV + cg * 8 + 4);
        UF8 w;
#pragma unroll
        for (int j = 0; j < 4; j++) w.h[j] = (f16)a0.a[j];
#pragma unroll
        for (int j = 0; j < 4; j++) w.h[j + 4] = (f16)a1.a[j];
        size_t frag = ((size_t)(o >> 4) * 8 + (cg >> 2)) * 512 + ((cg & 3) * 16 + (o & 15)) * 8;
        *(uint4*)(wp + frag) = w.u;
    }
}

// ---------------------------------------------------------------------------
// gemm_qkv v3: 2-MFMA f16 scheme. x staged as SINGLE f16 A-frags (error
// 2^-12 rel; staging VALU halves, LDS 32->16 KB, A ds-reads halve); w is
// split-f16 hi/lo (exact), so per (mt,nt,kt): acc = A*Bh + A*Bl — 16 MFMAs
// per kt vs v2's 24. Block (sb, oh, n) covers 32 s x 256 o. Grid (72,3,4)
// x 256 thr; wave = 32s x 64o (2x4 frags).
// ---------------------------------------------------------------------------
__global__ __launch_bounds__(256) void gemm_qkv(const float* __restrict__ x,
                                                const unsigned short* __restrict__ wh,
                                                const unsigned short* __restrict__ wl,
                                                const float* __restrict__ bias,
                                                f16* __restrict__ Qf,
                                                f16* __restrict__ Kf,
                                                f16* __restrict__ Vp) {
    int sb = blockIdx.x, oh = blockIdx.y, n = blockIdx.z;
    int tid  = threadIdx.x;
    int wid  = tid >> 6;
    int lane = tid & 63;
    int l15  = lane & 15;
    int quad = lane >> 4;
    int s0   = sb * 32;

    __shared__ unsigned short AH[8192];   // f16 bits, [kt 8][mt 2][lane 64][8]

    // ---- stage x strip -> f16 A-frag LDS ----
    {
        int cg = tid >> 5;          // 0..7
        int sl = tid & 31;          // s within strip
        const float* xb = x + (size_t)n * kC * kS + s0 + sl;
#pragma unroll
        for (int r = 0; r < 4; r++) {
            UF8 hv;
#pragma unroll
            for (int j = 0; j < 8; j++) {
                float v = xb[(size_t)(r * 64 + cg * 8 + j) * kS];
                hv.h[j] = (f16)v;
            }
            // c = r*64 + cg*8 + j: kt = r*2 + (cg>>2); lane-part ((cg&3)*16 + s&15)
            int off = (r * 2 + (cg >> 2)) * 1024 + (sl >> 4) * 512 + ((cg & 3) * 16 + (sl & 15)) * 8;
            *(uint4*)(&AH[off]) = hv.u;
        }
    }
    __syncthreads();

    const unsigned short* bhb = wh + ((size_t)(oh * 16 + wid * 4) * 8) * 512 + (size_t)lane * 8;
    const unsigned short* blb = wl + ((size_t)(oh * 16 + wid * 4) * 8) * 512 + (size_t)lane * 8;

    f32x4 acc[2][4] = {};
#pragma unroll
    for (int kt = 0; kt < 8; kt++) {
        f16x8 Bh[4], Bl[4];
#pragma unroll
        for (int nt = 0; nt < 4; nt++) {
            UF8 u;
            u.u = *(const uint4*)(bhb + (size_t)(nt * 8 + kt) * 512); Bh[nt] = u.v;
            u.u = *(const uint4*)(blb + (size_t)(nt * 8 + kt) * 512); Bl[nt] = u.v;
        }
        f16x8 A[2];
#pragma unroll
        for (int mt = 0; mt < 2; mt++) {
            UF8 u;
            u.u = *(const uint4*)(&AH[kt * 1024 + mt * 512 + lane * 8]); A[mt] = u.v;
        }
#pragma unroll
        for (int mt = 0; mt < 2; mt++)
#pragma unroll
            for (int nt = 0; nt < 4; nt++) {
                acc[mt][nt] = __builtin_amdgcn_mfma_f32_16x16x32_f16(A[mt], Bh[nt], acc[mt][nt], 0, 0, 0);
                acc[mt][nt] = __builtin_amdgcn_mfma_f32_16x16x32_f16(A[mt], Bl[nt], acc[mt][nt], 0, 0, 0);
            }
    }

    // Epilogue (r7-verified): D[row=s][col=o], row = quad*4+r, col = l15.
    constexpr float kQScale = 0.0625f * 1.4426950408889634f;
#pragma unroll
    for (int nt = 0; nt < 4; nt++) {
        int col = oh * 256 + wid * 64 + nt * 16 + l15;
        float bcol = bias[col];
        int h   = (col >> 5) & 7;
        int d   = col & 31;
        int nh  = n * 8 + h;
#pragma unroll
        for (int mt = 0; mt < 2; mt++) {
            int row0 = s0 + mt * 16 + quad * 4;
            if (oh == 2) {
                // V -> 32x32 A-frag layout, t-scrambled within each 16-row tile:
                // slot lane_t = (quad&1)*32 + d, j = (quad>>1)*4 + r (inverse of rho').
                UF4 w;
#pragma unroll
                for (int r = 0; r < 4; r++) w.v[r] = (f16)(acc[mt][nt][r] + bcol);
                size_t off = (((size_t)nh * 144 + sb * 2 + mt) * 64 + (quad & 1) * 32 + d) * 8
                             + (quad >> 1) * 4;
                *(ushort4*)(Vp + off) = w.su;
            } else if (oh == 0) {
#pragma unroll
                for (int r = 0; r < 4; r++)
                    Kf[((size_t)nh * kS + row0 + r) * kDH + d] = (f16)(acc[mt][nt][r] + bcol);
            } else {
#pragma unroll
                for (int r = 0; r < 4; r++)
                    Qf[((size_t)nh * kS + row0 + r) * kDH + d] =
                        (f16)((acc[mt][nt][r] + bcol) * kQScale);
            }
        }
    }
}

// ---------------------------------------------------------------------------
// attn v9: Q-tile 64 per wave (was 32). K/V loads per body are shared by two
// independent z-chains -> L2 traffic per query HALVES (r2 showed attn at the
// per-XCD L2 roofline: 680 MB / 45.7 us = 14.9 TB/s aggregate) and per-wave
// ILP doubles. Keeps 3-wave t-split, max-free softmax, ping-pong x2, dot2
// lsum, swizzled Ored combine. Grid (8 h, 36 qw, 4 n) x 192 thr.
// ---------------------------------------------------------------------------
#if __has_builtin(__builtin_amdgcn_fdot2)
#define LADD(acc, lou, hiu)                                                 \
    acc = __builtin_amdgcn_fdot2(__builtin_bit_cast(f16x2, lou), one2, acc, false); \
    acc = __builtin_amdgcn_fdot2(__builtin_bit_cast(f16x2, hiu), one2, acc, false);
#else
#define LADD(acc, lou, hiu)                                                 \
    {                                                                       \
        UF4 t; t.u.x = lou; t.u.y = hiu;                                    \
        acc += (float)t.v[0] + (float)t.v[1] + (float)t.v[2] + (float)t.v[3]; \
    }
#endif

#define SUBTILE(zq, VC, sidx, roff, lacc, oaccv)                            \
    {                                                                       \
        float e0 = EXP2(zq[roff + 0]), e1 = EXP2(zq[roff + 1]);             \
        float e2 = EXP2(zq[roff + 2]), e3 = EXP2(zq[roff + 3]);             \
        float e4 = EXP2(zq[roff + 4]), e5 = EXP2(zq[roff + 5]);             \
        float e6 = EXP2(zq[roff + 6]), e7 = EXP2(zq[roff + 7]);             \
        UF8 pw;                                                             \
        pw.u.x = pk2(e0, e1); pw.u.y = pk2(e2, e3);                         \
        pw.u.z = pk2(e4, e5); pw.u.w = pk2(e6, e7);                         \
        LADD(lacc, pw.u.x, pw.u.y)                                          \
        LADD(lacc, pw.u.z, pw.u.w)                                          \
        __builtin_amdgcn_s_setprio(1);                                      \
        oaccv = __builtin_amdgcn_mfma_f32_32x32x16_f16(VC[sidx], pw.v,      \
                                                       oaccv, 0, 0, 0);     \
        __builtin_amdgcn_s_setprio(0);                                      \
    }

#define ATTN_BODY(KC, VC, KN, VN)                                           \
    {                                                                       \
        UF8 u;                                                              \
        u.u = *(const uint4*)(kp + 1024);       KN[0] = u.v;                \
        u.u = *(const uint4*)(kp + 1040);       KN[1] = u.v;                \
        u.u = *(const uint4*)(vp + 1024);       VN[0] = u.v;                \
        u.u = *(const uint4*)(vp + 1536);       VN[1] = u.v;                \
        __builtin_amdgcn_s_setprio(1);                                      \
        f32x16 z0 = __builtin_amdgcn_mfma_f32_32x32x16_f16(KC[0], qf[0], zc, 0, 0, 0); \
        z0 = __builtin_amdgcn_mfma_f32_32x32x16_f16(KC[1], qf[1], z0, 0, 0, 0); \
        __builtin_amdgcn_s_setprio(0);                                      \
        SUBTILE(z0, VC, 0, 0, lsumA0, oacc0)                                \
        SUBTILE(z0, VC, 1, 8, lsumB0, oacc0)                                \
        __builtin_amdgcn_s_setprio(1);                                      \
        f32x16 z1 = __builtin_amdgcn_mfma_f32_32x32x16_f16(KC[0], qf[2], zc, 0, 0, 0); \
        z1 = __builtin_amdgcn_mfma_f32_32x32x16_f16(KC[1], qf[3], z1, 0, 0, 0); \
        __builtin_amdgcn_s_setprio(0);                                      \
        SUBTILE(z1, VC, 0, 0, lsumA1, oacc1)                                \
        SUBTILE(z1, VC, 1, 8, lsumB1, oacc1)                                \
        kp += 1024;                                                         \
        vp += 1024;                                                         \
    }

__global__ __launch_bounds__(192, 2) void attn_f16(const f16* __restrict__ Qf,
                                                   const f16* __restrict__ Kf,
                                                   const f16* __restrict__ Vp,
                                                   f16* __restrict__ attnF) {
    int h = blockIdx.x, qw = blockIdx.y, n = blockIdx.z;
    int nh = n * 8 + h;
    int tid  = threadIdx.x;
    int wid  = tid >> 6;           // t-chunk 0..2
    int lane = tid & 63;
    int c    = lane & 31;
    int hi   = lane >> 5;
    int sqb  = qw * 64;

    __shared__ __align__(16) float Ored[2][2][64][16];  // [src wave-1][qhalf][lane][reg swz]
    __shared__ float Lred[2][2][32];                    // [src wave-1][qhalf][col]

    // K: row-major [nh][s][32]; lane reads row (t0 + c), d-chunk hi*8 (+16 for kc=1)
    const f16* kp = Kf + (size_t)nh * kS * kDH + ((size_t)wid * 768 + c) * kDH + hi * 8;
    // V: scrambled A-frag [nh][tile 144][lane 64][8]
    const f16* vp = Vp + (size_t)nh * 144 * 512 + (size_t)wid * 48 * 512 + (size_t)lane * 8;

    f16x8 qf[4];
    {
        const f16* Qb = Qf + (size_t)nh * kS * kDH;
        UF8 u;
        u.u = *(const uint4*)(Qb + (size_t)(sqb + c) * kDH + hi * 8);           qf[0] = u.v;
        u.u = *(const uint4*)(Qb + (size_t)(sqb + c) * kDH + hi * 8 + 16);      qf[1] = u.v;
        u.u = *(const uint4*)(Qb + (size_t)(sqb + 32 + c) * kDH + hi * 8);      qf[2] = u.v;
        u.u = *(const uint4*)(Qb + (size_t)(sqb + 32 + c) * kDH + hi * 8 + 16); qf[3] = u.v;
    }

    f32x16 zc    = {};   // hoisted zero C-operand
    f32x16 oacc0 = {};   // qhalf0: O^T[d = (reg&3)+8*(reg>>2)+4*hi][sq = c]
    f32x16 oacc1 = {};   // qhalf1
    float lsumA0 = 0.f, lsumB0 = 0.f, lsumA1 = 0.f, lsumB1 = 0.f;
    const f16x2 one2 = {(_Float16)1.0f, (_Float16)1.0f};

    f16x8 kA[2], kB[2], vA[2], vB[2];
    {
        UF8 u;
        u.u = *(const uint4*)(kp);        kA[0] = u.v;
        u.u = *(const uint4*)(kp + 16);   kA[1] = u.v;
        u.u = *(const uint4*)(vp);        vA[0] = u.v;
        u.u = *(const uint4*)(vp + 512);  vA[1] = u.v;
    }

    // 24 bodies of 32 t per wave, ping-pong x2; tail over-reads land in the
    // adjacent ws buffers (allocated, values unused).
    for (int it = 0; it < 12; it++) {
        ATTN_BODY(kA, vA, kB, vB)
        ATTN_BODY(kB, vB, kA, vA)
    }

    float lsum0 = lsumA0 + lsumB0;
    float lsum1 = lsumA1 + lsumB1;
    // lanes c and c+32 hold complementary t-halves -> single cross-half reduce
    lsum0 += __shfl_xor(lsum0, 32);
    lsum1 += __shfl_xor(lsum1, 32);

    // cross-wave combine: waves 1,2 dump partials; wave 0 reduces + writes.
    // Column slot swizzled by g ^ ((lane>>1)&3) (kills the r1 bank conflicts).
    int gsw = (lane >> 1) & 3;
    if (wid > 0) {
#pragma unroll
        for (int g = 0; g < 4; g++) {
            f32x4 t0 = {oacc0[g * 4 + 0], oacc0[g * 4 + 1], oacc0[g * 4 + 2], oacc0[g * 4 + 3]};
            f32x4 t1 = {oacc1[g * 4 + 0], oacc1[g * 4 + 1], oacc1[g * 4 + 2], oacc1[g * 4 + 3]};
            *(f32x4*)(&Ored[wid - 1][0][lane][(g ^ gsw) * 4]) = t0;
            *(f32x4*)(&Ored[wid - 1][1][lane][(g ^ gsw) * 4]) = t1;
        }
        if (lane < 32) {
            Lred[wid - 1][0][lane] = lsum0;
            Lred[wid - 1][1][lane] = lsum1;
        }
    }
    __syncthreads();
    if (wid != 0) return;

#pragma unroll
    for (int g = 0; g < 4; g++) {
        f32x4 a0 = *(const f32x4*)(&Ored[0][0][lane][(g ^ gsw) * 4]);
        f32x4 b0 = *(const f32x4*)(&Ored[1][0][lane][(g ^ gsw) * 4]);
        f32x4 a1 = *(const f32x4*)(&Ored[0][1][lane][(g ^ gsw) * 4]);
        f32x4 b1 = *(const f32x4*)(&Ored[1][1][lane][(g ^ gsw) * 4]);
#pragma unroll
        for (int r = 0; r < 4; r++) {
            oacc0[g * 4 + r] += a0[r] + b0[r];
            oacc1[g * 4 + r] += a1[r] + b1[r];
        }
    }
    lsum0 += Lred[0][0][c] + Lred[1][0][c];
    lsum1 += Lred[0][1][c] + Lred[1][1][c];

    // epilogue: normalize; write attnF in gemm_out B-frag order.
    // reg group g holds d = 8g + 4hi + r -> lane_t = g*16 + (c&15), j = 4hi + r.
#define EPI(oaccv, lsumv, p)                                                \
    {                                                                       \
        float inv = 1.0f / lsumv;                                           \
        int stile = qw * 4 + (p) * 2 + (c >> 4);                            \
        size_t base = ((size_t)(n * 144 + stile) * 8 + h) * 512             \
                      + (size_t)(c & 15) * 8 + hi * 4;                      \
        _Pragma("unroll")                                                   \
        for (int g = 0; g < 4; g++) {                                       \
            UF4 w;                                                          \
            _Pragma("unroll")                                               \
            for (int r = 0; r < 4; r++) w.v[r] = (f16)(oaccv[g * 4 + r] * inv); \
            *(uint2*)(attnF + base + g * 128) = w.u;                        \
        }                                                                   \
    }
    EPI(oacc0, lsum0, 0)
    EPI(oacc1, lsum1, 1)
#undef EPI
}

// ---------------------------------------------------------------------------
// gemm_out (r7-r10-verified): LDS-free, fragment-direct, double buffer.
// Wave computes 32o x 64s (2x4 frags), K=256 in 8 ktiles. Grid (8,36,4).
// ---------------------------------------------------------------------------
__global__ __launch_bounds__(64) void gemm_out(const f16* __restrict__ wp,
                                               const f16* __restrict__ attnF,
                                               const float* __restrict__ bias,
                                               float* __restrict__ out) {
    int ob = blockIdx.x, sb = blockIdx.y, n = blockIdx.z;
    int lane = threadIdx.x;
    int l15  = lane & 15;
    int quad = lane >> 4;

    const f16* ap = wp + ((size_t)(ob * 2) * 8) * 512 + (size_t)lane * 8;
    const f16* bp = attnF + ((size_t)(n * 144 + sb * 4) * 8) * 512 + (size_t)lane * 8;

    f16x8 af[2], bf[4], naf[2], nbf[4];
    {
        UF8 u;
#pragma unroll
        for (int i = 0; i < 2; i++) { u.u = *(const uint4*)(ap + (i * 8) * 512); af[i] = u.v; }
#pragma unroll
        for (int i = 0; i < 4; i++) { u.u = *(const uint4*)(bp + (i * 8) * 512); bf[i] = u.v; }
    }

    f32x4 acc[2][4] = {};
#pragma unroll
    for (int kt = 0; kt < 8; kt++) {
        if (kt < 7) {
            UF8 u;
#pragma unroll
            for (int i = 0; i < 2; i++) { u.u = *(const uint4*)(ap + (i * 8 + kt + 1) * 512); naf[i] = u.v; }
#pragma unroll
            for (int i = 0; i < 4; i++) { u.u = *(const uint4*)(bp + (i * 8 + kt + 1) * 512); nbf[i] = u.v; }
        }
#pragma unroll
        for (int mt = 0; mt < 2; mt++)
#pragma unroll
            for (int nt = 0; nt < 4; nt++)
                acc[mt][nt] = __builtin_amdgcn_mfma_f32_16x16x32_f16(af[mt], bf[nt],
                                                                     acc[mt][nt], 0, 0, 0);
#pragma unroll
        for (int i = 0; i < 2; i++) af[i] = naf[i];
#pragma unroll
        for (int i = 0; i < 4; i++) bf[i] = nbf[i];
    }

#pragma unroll
    for (int mt = 0; mt < 2; mt++) {
        int row0 = ob * 32 + mt * 16 + quad * 4;   // o
#pragma unroll
        for (int nt = 0; nt < 4; nt++) {
            int col = sb * 64 + nt * 16 + l15;     // s
#pragma unroll
            for (int r = 0; r < 4; r++)
                out[((size_t)n * kDV + row0 + r) * kS + col] = acc[mt][nt][r] + bias[row0 + r];
        }
    }
}

// ---------------------------------------------------------------------------
extern "C" void kernel_launch(void* const* d_in, const int* in_sizes, int n_in,
                              void* d_out, int out_size, void* d_ws, size_t ws_size,
                              hipStream_t stream) {
    const float* x      = (const float*)d_in[0];
    const float* w_qkv  = (const float*)d_in[1];
    const float* b_qkv  = (const float*)d_in[2];
    const float* w_proj = (const float*)d_in[3];
    const float* b_proj = (const float*)d_in[4];
    float* out = (float*)d_out;

    constexpr size_t kXE = (size_t)kN * kS * kC;     // 2,359,296
    unsigned short* wh = (unsigned short*)d_ws;      // w_qkv B-frag f16-hi
    unsigned short* wl = wh + 196608;                // w_qkv B-frag f16-lo
    f16* wpF   = (f16*)(wl + 196608);                // w_proj A-frag f16
    f16* Qf    = wpF + 65536;                        // [32 nh][2304][32]
    f16* Kf    = Qf + kXE;
    f16* Vp    = Kf + kXE;                           // [32 nh][144][64][8] scrambled A-frag
    f16* attnF = Vp + kXE;                           // B-frag [n][144][8][512]

    prep_w<<<dim3(128), 256, 0, stream>>>(w_qkv, w_proj, wh, wl, wpF);

    gemm_qkv<<<dim3(72, 3, 4), 256, 0, stream>>>(x, wh, wl, b_qkv, Qf, Kf, Vp);

    attn_f16<<<dim3(8, 36, 4), 192, 0, stream>>>(Qf, Kf, Vp, attnF);

    gemm_out<<<dim3(8, 36, 4), 64, 0, stream>>>(wpF, attnF, b_proj, out);
}

// Round 4
// 118.384 us; speedup vs baseline: 1.1558x; 1.0304x over previous
//
#include <hip/hip_runtime.h>
#include <cstdint>

// Problem constants
constexpr int kN   = 4;
constexpr int kC   = 256;
constexpr int kS   = 2304;   // 48*48
constexpr int kDK  = 256;
constexpr int kDV  = 256;
constexpr int kDH  = 32;     // head dim
constexpr int kO   = 768;    // 2*DK + DV

typedef __bf16    bf16x8 __attribute__((ext_vector_type(8)));
typedef float     f32x4  __attribute__((ext_vector_type(4)));
typedef float     f32x16 __attribute__((ext_vector_type(16)));
typedef _Float16  f16;
typedef _Float16  f16x2  __attribute__((ext_vector_type(2)));
typedef _Float16  f16x4  __attribute__((ext_vector_type(4)));
typedef _Float16  f16x8  __attribute__((ext_vector_type(8)));

union U4  { uint4 u; bf16x8 v; unsigned short s[8]; };
union F4  { float4 f; float a[4]; };
union UF8 { uint4 u; f16x8 v; f16 h[8]; };
union UF4 { uint2 u; f16x4 v; ushort4 su; };

#if __has_builtin(__builtin_amdgcn_exp2f)
#define EXP2(x) __builtin_amdgcn_exp2f(x)
#else
#define EXP2(x) exp2f(x)
#endif

__device__ inline unsigned int pk2(float a, float b) {
    auto p = __builtin_amdgcn_cvt_pkrtz(a, b);
    return __builtin_bit_cast(unsigned int, p);
}
// f16 hi/lo split: h captures 11 mantissa bits, l the next 11 (~22-bit exact).
__device__ inline void split2f(float v, f16& h, f16& l) {
    h = (f16)v;
    l = (f16)(v - (float)h);
}

// Fragment layouts:
// 16x16x32 (correctness-verified rounds 6-10; dtype-independent):
//   A/B-frag elem (row, k): lane = ((k>>3)&3)*16 + (row&15), j = k&7
//   C-layout: D[row = (lane>>4)*4 + reg][col = lane&15].
// 32x32x16 (attn core, r1-verified):
//   A-frag (row, k): lane = (k>>3)*32 + (row&31), j = k&7  (B symmetric, col=lane&31)
//   C-layout: D[row = (reg&3) + 8*(reg>>2) + 4*(lane>>5)][col = lane&31].

// ---------------------------------------------------------------------------
// prep_w (r3-verified): w_qkv -> SPLIT-F16 B-frags wh/wl [otile 48][kt 8]
// [lane][8]; w_proj -> f16 A-frag wp. Grid 128.
// ---------------------------------------------------------------------------
__global__ __launch_bounds__(256) void prep_w(const float* __restrict__ w_qkv,
                                              const float* __restrict__ w_proj,
                                              unsigned short* __restrict__ wh,
                                              unsigned short* __restrict__ wl,
                                              f16* __restrict__ wp) {
    int idx = blockIdx.x * 256 + threadIdx.x;
    if (idx < 24576) {           // w_qkv: 768 o x 32 c-groups
        int o = idx >> 5, cg = idx & 31;
        F4 a0, a1;
        a0.f = *(const float4*)(w_qkv + (size_t)o * kC + cg * 8);
        a1.f = *(const float4*)(w_qkv + (size_t)o * kC + cg * 8 + 4);
        UF8 hv, lv;
#pragma unroll
        for (int j = 0; j < 4; j++) split2f(a0.a[j], hv.h[j], lv.h[j]);
#pragma unroll
        for (int j = 0; j < 4; j++) split2f(a1.a[j], hv.h[j + 4], lv.h[j + 4]);
        size_t frag = ((size_t)(o >> 4) * 8 + (cg >> 2)) * 512 + ((cg & 3) * 16 + (o & 15)) * 8;
        *(uint4*)(wh + frag) = hv.u;
        *(uint4*)(wl + frag) = lv.u;
    } else {                     // w_proj: 256 o x 32 dv-groups
        int i2 = idx - 24576;
        int o = i2 >> 5, cg = i2 & 31;
        F4 a0, a1;
        a0.f = *(const float4*)(w_proj + (size_t)o * kDV + cg * 8);
        a1.f = *(const float4*)(w_proj + (size_t)o * kDV + cg * 8 + 4);
        UF8 w;
#pragma unroll
        for (int j = 0; j < 4; j++) w.h[j] = (f16)a0.a[j];
#pragma unroll
        for (int j = 0; j < 4; j++) w.h[j + 4] = (f16)a1.a[j];
        size_t frag = ((size_t)(o >> 4) * 8 + (cg >> 2)) * 512 + ((cg & 3) * 16 + (o & 15)) * 8;
        *(uint4*)(wp + frag) = w.u;
    }
}

// ---------------------------------------------------------------------------
// gemm_qkv v4: w-L2-traffic cut. 512-thr blocks (8 waves) cover 64 s x 256 o;
// each wave = 64s x 32o (acc 4x2, only 32 regs). B-bytes/wave amortize over
// 64 s-rows -> w L2 traffic halves vs v3 (221 -> 110 MB). x staged once per
// block as single-f16 A-frags (32 KB LDS, 32 scalar loads/thread). 2-MFMA
// split-f16-w scheme (r3-verified numerics). Grid (36, 3, 4) x 512 thr.
// ---------------------------------------------------------------------------
__global__ __launch_bounds__(512) void gemm_qkv(const float* __restrict__ x,
                                                const unsigned short* __restrict__ wh,
                                                const unsigned short* __restrict__ wl,
                                                const float* __restrict__ bias,
                                                f16* __restrict__ Qf,
                                                f16* __restrict__ Kf,
                                                f16* __restrict__ Vp) {
    int sb = blockIdx.x, oh = blockIdx.y, n = blockIdx.z;
    int tid  = threadIdx.x;
    int wid  = tid >> 6;          // o-strip 0..7 (32 o each)
    int lane = tid & 63;
    int l15  = lane & 15;
    int quad = lane >> 4;
    int s0   = sb * 64;

    __shared__ unsigned short AH[16384];   // f16 bits, [kt 8][mt 4][lane 64][8]

    // ---- stage x strip [64 s][256 c] -> f16 A-frag LDS ----
    {
        int cg = tid >> 6;          // 0..7
        int sl = tid & 63;          // s within strip
        const float* xb = x + (size_t)n * kC * kS + s0 + sl;
#pragma unroll
        for (int r = 0; r < 4; r++) {
            UF8 hv;
#pragma unroll
            for (int j = 0; j < 8; j++)
                hv.h[j] = (f16)xb[(size_t)(r * 64 + cg * 8 + j) * kS];
            // c = r*64 + cg*8 + j: kt = r*2 + (cg>>2); lane = (cg&3)*16 + (sl&15)
            int off = (r * 2 + (cg >> 2)) * 2048 + (sl >> 4) * 512
                      + ((cg & 3) * 16 + (sl & 15)) * 8;
            *(uint4*)(&AH[off]) = hv.u;
        }
    }
    __syncthreads();

    const unsigned short* bhb = wh + ((size_t)(oh * 16 + wid * 2) * 8) * 512 + (size_t)lane * 8;
    const unsigned short* blb = wl + ((size_t)(oh * 16 + wid * 2) * 8) * 512 + (size_t)lane * 8;

    f32x4 acc[4][2] = {};
#pragma unroll
    for (int kt = 0; kt < 8; kt++) {
        f16x8 Bh[2], Bl[2];
#pragma unroll
        for (int nt = 0; nt < 2; nt++) {
            UF8 u;
            u.u = *(const uint4*)(bhb + (size_t)(nt * 8 + kt) * 512); Bh[nt] = u.v;
            u.u = *(const uint4*)(blb + (size_t)(nt * 8 + kt) * 512); Bl[nt] = u.v;
        }
        f16x8 A[4];
#pragma unroll
        for (int mt = 0; mt < 4; mt++) {
            UF8 u;
            u.u = *(const uint4*)(&AH[kt * 2048 + mt * 512 + lane * 8]); A[mt] = u.v;
        }
#pragma unroll
        for (int mt = 0; mt < 4; mt++)
#pragma unroll
            for (int nt = 0; nt < 2; nt++) {
                acc[mt][nt] = __builtin_amdgcn_mfma_f32_16x16x32_f16(A[mt], Bh[nt], acc[mt][nt], 0, 0, 0);
                acc[mt][nt] = __builtin_amdgcn_mfma_f32_16x16x32_f16(A[mt], Bl[nt], acc[mt][nt], 0, 0, 0);
            }
    }

    // Epilogue (r7-verified): D[row=s][col=o], row = quad*4+r, col = l15.
    constexpr float kQScale = 0.0625f * 1.4426950408889634f;
#pragma unroll
    for (int nt = 0; nt < 2; nt++) {
        int col = oh * 256 + wid * 32 + nt * 16 + l15;
        float bcol = bias[col];
        int h   = (col >> 5) & 7;
        int d   = col & 31;
        int nh  = n * 8 + h;
#pragma unroll
        for (int mt = 0; mt < 4; mt++) {
            int row0 = s0 + mt * 16 + quad * 4;
            if (oh == 2) {
                // V -> 32x32 A-frag layout, t-scrambled within each 16-row tile:
                // slot lane_t = (quad&1)*32 + d, j = (quad>>1)*4 + r (inverse of rho').
                UF4 w;
#pragma unroll
                for (int r = 0; r < 4; r++) w.v[r] = (f16)(acc[mt][nt][r] + bcol);
                size_t off = (((size_t)nh * 144 + sb * 4 + mt) * 64 + (quad & 1) * 32 + d) * 8
                             + (quad >> 1) * 4;
                *(ushort4*)(Vp + off) = w.su;
            } else if (oh == 0) {
#pragma unroll
                for (int r = 0; r < 4; r++)
                    Kf[((size_t)nh * kS + row0 + r) * kDH + d] = (f16)(acc[mt][nt][r] + bcol);
            } else {
#pragma unroll
                for (int r = 0; r < 4; r++)
                    Qf[((size_t)nh * kS + row0 + r) * kDH + d] =
                        (f16)((acc[mt][nt][r] + bcol) * kQScale);
            }
        }
    }
}

// ---------------------------------------------------------------------------
// attn v9 (r3-verified) + launch_bounds min-waves 2 -> 3 (hand count ~130
// combined regs; cap at 3/SIMD is free, guarantees occupancy).
// ---------------------------------------------------------------------------
#if __has_builtin(__builtin_amdgcn_fdot2)
#define LADD(acc, lou, hiu)                                                 \
    acc = __builtin_amdgcn_fdot2(__builtin_bit_cast(f16x2, lou), one2, acc, false); \
    acc = __builtin_amdgcn_fdot2(__builtin_bit_cast(f16x2, hiu), one2, acc, false);
#else
#define LADD(acc, lou, hiu)                                                 \
    {                                                                       \
        UF4 t; t.u.x = lou; t.u.y = hiu;                                    \
        acc += (float)t.v[0] + (float)t.v[1] + (float)t.v[2] + (float)t.v[3]; \
    }
#endif

#define SUBTILE(zq, VC, sidx, roff, lacc, oaccv)                            \
    {                                                                       \
        float e0 = EXP2(zq[roff + 0]), e1 = EXP2(zq[roff + 1]);             \
        float e2 = EXP2(zq[roff + 2]), e3 = EXP2(zq[roff + 3]);             \
        float e4 = EXP2(zq[roff + 4]), e5 = EXP2(zq[roff + 5]);             \
        float e6 = EXP2(zq[roff + 6]), e7 = EXP2(zq[roff + 7]);             \
        UF8 pw;                                                             \
        pw.u.x = pk2(e0, e1); pw.u.y = pk2(e2, e3);                         \
        pw.u.z = pk2(e4, e5); pw.u.w = pk2(e6, e7);                         \
        LADD(lacc, pw.u.x, pw.u.y)                                          \
        LADD(lacc, pw.u.z, pw.u.w)                                          \
        __builtin_amdgcn_s_setprio(1);                                      \
        oaccv = __builtin_amdgcn_mfma_f32_32x32x16_f16(VC[sidx], pw.v,      \
                                                       oaccv, 0, 0, 0);     \
        __builtin_amdgcn_s_setprio(0);                                      \
    }

#define ATTN_BODY(KC, VC, KN, VN)                                           \
    {                                                                       \
        UF8 u;                                                              \
        u.u = *(const uint4*)(kp + 1024);       KN[0] = u.v;                \
        u.u = *(const uint4*)(kp + 1040);       KN[1] = u.v;                \
        u.u = *(const uint4*)(vp + 1024);       VN[0] = u.v;                \
        u.u = *(const uint4*)(vp + 1536);       VN[1] = u.v;                \
        __builtin_amdgcn_s_setprio(1);                                      \
        f32x16 z0 = __builtin_amdgcn_mfma_f32_32x32x16_f16(KC[0], qf[0], zc, 0, 0, 0); \
        z0 = __builtin_amdgcn_mfma_f32_32x32x16_f16(KC[1], qf[1], z0, 0, 0, 0); \
        __builtin_amdgcn_s_setprio(0);                                      \
        SUBTILE(z0, VC, 0, 0, lsumA0, oacc0)                                \
        SUBTILE(z0, VC, 1, 8, lsumB0, oacc0)                                \
        __builtin_amdgcn_s_setprio(1);                                      \
        f32x16 z1 = __builtin_amdgcn_mfma_f32_32x32x16_f16(KC[0], qf[2], zc, 0, 0, 0); \
        z1 = __builtin_amdgcn_mfma_f32_32x32x16_f16(KC[1], qf[3], z1, 0, 0, 0); \
        __builtin_amdgcn_s_setprio(0);                                      \
        SUBTILE(z1, VC, 0, 0, lsumA1, oacc1)                                \
        SUBTILE(z1, VC, 1, 8, lsumB1, oacc1)                                \
        kp += 1024;                                                         \
        vp += 1024;                                                         \
    }

__global__ __launch_bounds__(192, 3) void attn_f16(const f16* __restrict__ Qf,
                                                   const f16* __restrict__ Kf,
                                                   const f16* __restrict__ Vp,
                                                   f16* __restrict__ attnF) {
    int h = blockIdx.x, qw = blockIdx.y, n = blockIdx.z;
    int nh = n * 8 + h;
    int tid  = threadIdx.x;
    int wid  = tid >> 6;           // t-chunk 0..2
    int lane = tid & 63;
    int c    = lane & 31;
    int hi   = lane >> 5;
    int sqb  = qw * 64;

    __shared__ __align__(16) float Ored[2][2][64][16];  // [src wave-1][qhalf][lane][reg swz]
    __shared__ float Lred[2][2][32];                    // [src wave-1][qhalf][col]

    // K: row-major [nh][s][32]; lane reads row (t0 + c), d-chunk hi*8 (+16 for kc=1)
    const f16* kp = Kf + (size_t)nh * kS * kDH + ((size_t)wid * 768 + c) * kDH + hi * 8;
    // V: scrambled A-frag [nh][tile 144][lane 64][8]
    const f16* vp = Vp + (size_t)nh * 144 * 512 + (size_t)wid * 48 * 512 + (size_t)lane * 8;

    f16x8 qf[4];
    {
        const f16* Qb = Qf + (size_t)nh * kS * kDH;
        UF8 u;
        u.u = *(const uint4*)(Qb + (size_t)(sqb + c) * kDH + hi * 8);           qf[0] = u.v;
        u.u = *(const uint4*)(Qb + (size_t)(sqb + c) * kDH + hi * 8 + 16);      qf[1] = u.v;
        u.u = *(const uint4*)(Qb + (size_t)(sqb + 32 + c) * kDH + hi * 8);      qf[2] = u.v;
        u.u = *(const uint4*)(Qb + (size_t)(sqb + 32 + c) * kDH + hi * 8 + 16); qf[3] = u.v;
    }

    f32x16 zc    = {};   // hoisted zero C-operand
    f32x16 oacc0 = {};   // qhalf0: O^T[d = (reg&3)+8*(reg>>2)+4*hi][sq = c]
    f32x16 oacc1 = {};   // qhalf1
    float lsumA0 = 0.f, lsumB0 = 0.f, lsumA1 = 0.f, lsumB1 = 0.f;
    const f16x2 one2 = {(_Float16)1.0f, (_Float16)1.0f};

    f16x8 kA[2], kB[2], vA[2], vB[2];
    {
        UF8 u;
        u.u = *(const uint4*)(kp);        kA[0] = u.v;
        u.u = *(const uint4*)(kp + 16);   kA[1] = u.v;
        u.u = *(const uint4*)(vp);        vA[0] = u.v;
        u.u = *(const uint4*)(vp + 512);  vA[1] = u.v;
    }

    // 24 bodies of 32 t per wave, ping-pong x2; tail over-reads land in the
    // adjacent ws buffers (allocated, values unused).
    for (int it = 0; it < 12; it++) {
        ATTN_BODY(kA, vA, kB, vB)
        ATTN_BODY(kB, vB, kA, vA)
    }

    float lsum0 = lsumA0 + lsumB0;
    float lsum1 = lsumA1 + lsumB1;
    // lanes c and c+32 hold complementary t-halves -> single cross-half reduce
    lsum0 += __shfl_xor(lsum0, 32);
    lsum1 += __shfl_xor(lsum1, 32);

    // cross-wave combine: waves 1,2 dump partials; wave 0 reduces + writes.
    // Column slot swizzled by g ^ ((lane>>1)&3) (kills the r1 bank conflicts).
    int gsw = (lane >> 1) & 3;
    if (wid > 0) {
#pragma unroll
        for (int g = 0; g < 4; g++) {
            f32x4 t0 = {oacc0[g * 4 + 0], oacc0[g * 4 + 1], oacc0[g * 4 + 2], oacc0[g * 4 + 3]};
            f32x4 t1 = {oacc1[g * 4 + 0], oacc1[g * 4 + 1], oacc1[g * 4 + 2], oacc1[g * 4 + 3]};
            *(f32x4*)(&Ored[wid - 1][0][lane][(g ^ gsw) * 4]) = t0;
            *(f32x4*)(&Ored[wid - 1][1][lane][(g ^ gsw) * 4]) = t1;
        }
        if (lane < 32) {
            Lred[wid - 1][0][lane] = lsum0;
            Lred[wid - 1][1][lane] = lsum1;
        }
    }
    __syncthreads();
    if (wid != 0) return;

#pragma unroll
    for (int g = 0; g < 4; g++) {
        f32x4 a0 = *(const f32x4*)(&Ored[0][0][lane][(g ^ gsw) * 4]);
        f32x4 b0 = *(const f32x4*)(&Ored[1][0][lane][(g ^ gsw) * 4]);
        f32x4 a1 = *(const f32x4*)(&Ored[0][1][lane][(g ^ gsw) * 4]);
        f32x4 b1 = *(const f32x4*)(&Ored[1][1][lane][(g ^ gsw) * 4]);
#pragma unroll
        for (int r = 0; r < 4; r++) {
            oacc0[g * 4 + r] += a0[r] + b0[r];
            oacc1[g * 4 + r] += a1[r] + b1[r];
        }
    }
    lsum0 += Lred[0][0][c] + Lred[1][0][c];
    lsum1 += Lred[0][1][c] + Lred[1][1][c];

    // epilogue: normalize; write attnF in gemm_out B-frag order.
    // reg group g holds d = 8g + 4hi + r -> lane_t = g*16 + (c&15), j = 4hi + r.
#define EPI(oaccv, lsumv, p)                                                \
    {                                                                       \
        float inv = 1.0f / lsumv;                                           \
        int stile = qw * 4 + (p) * 2 + (c >> 4);                            \
        size_t base = ((size_t)(n * 144 + stile) * 8 + h) * 512             \
                      + (size_t)(c & 15) * 8 + hi * 4;                      \
        _Pragma("unroll")                                                   \
        for (int g = 0; g < 4; g++) {                                       \
            UF4 w;                                                          \
            _Pragma("unroll")                                               \
            for (int r = 0; r < 4; r++) w.v[r] = (f16)(oaccv[g * 4 + r] * inv); \
            *(uint2*)(attnF + base + g * 128) = w.u;                        \
        }                                                                   \
    }
    EPI(oacc0, lsum0, 0)
    EPI(oacc1, lsum1, 1)
#undef EPI
}

// ---------------------------------------------------------------------------
// gemm_out v2: K-split x2. 128-thr blocks (2 waves); wave wid handles kt
// wid*4..wid*4+3 (24 loads, 32 MFMAs — half the r3 chain), combine via one
// xor-swizzled LDS dump (plain [lane][32] would 8-way conflict at 128B
// stride). Waves 1152 -> 2304 (9/CU) for the latency-bound phase.
// Grid (8, 36, 4) x 128 thr.
// ---------------------------------------------------------------------------
__global__ __launch_bounds__(128) void gemm_out(const f16* __restrict__ wp,
                                                const f16* __restrict__ attnF,
                                                const float* __restrict__ bias,
                                                float* __restrict__ out) {
    int ob = blockIdx.x, sb = blockIdx.y, n = blockIdx.z;
    int tid  = threadIdx.x;
    int wid  = tid >> 6;          // K-half 0..1
    int lane = tid & 63;
    int l15  = lane & 15;
    int quad = lane >> 4;

    __shared__ __align__(16) float Ocomb[64][32];   // 8 KB, xor-swizzled columns

    const f16* ap = wp + ((size_t)(ob * 2) * 8 + wid * 4) * 512 + (size_t)lane * 8;
    const f16* bp = attnF + ((size_t)(n * 144 + sb * 4) * 8 + wid * 4) * 512 + (size_t)lane * 8;

    f16x8 af[2], bf[4], naf[2], nbf[4];
    {
        UF8 u;
#pragma unroll
        for (int i = 0; i < 2; i++) { u.u = *(const uint4*)(ap + (i * 8) * 512); af[i] = u.v; }
#pragma unroll
        for (int i = 0; i < 4; i++) { u.u = *(const uint4*)(bp + (i * 8) * 512); bf[i] = u.v; }
    }

    f32x4 acc[2][4] = {};
#pragma unroll
    for (int t = 0; t < 4; t++) {
        if (t < 3) {
            UF8 u;
#pragma unroll
            for (int i = 0; i < 2; i++) { u.u = *(const uint4*)(ap + (i * 8 + t + 1) * 512); naf[i] = u.v; }
#pragma unroll
            for (int i = 0; i < 4; i++) { u.u = *(const uint4*)(bp + (i * 8 + t + 1) * 512); nbf[i] = u.v; }
        }
#pragma unroll
        for (int mt = 0; mt < 2; mt++)
#pragma unroll
            for (int nt = 0; nt < 4; nt++)
                acc[mt][nt] = __builtin_amdgcn_mfma_f32_16x16x32_f16(af[mt], bf[nt],
                                                                     acc[mt][nt], 0, 0, 0);
#pragma unroll
        for (int i = 0; i < 2; i++) af[i] = naf[i];
#pragma unroll
        for (int i = 0; i < 4; i++) bf[i] = nbf[i];
    }

    // cross-wave K combine: wave 1 dumps, wave 0 adds.
    int csw = lane & 7;
    if (wid == 1) {
#pragma unroll
        for (int mt = 0; mt < 2; mt++)
#pragma unroll
            for (int nt = 0; nt < 4; nt++) {
                int g = mt * 4 + nt;
                *(f32x4*)(&Ocomb[lane][(g ^ csw) * 4]) = acc[mt][nt];
            }
    }
    __syncthreads();
    if (wid != 0) return;

#pragma unroll
    for (int mt = 0; mt < 2; mt++) {
        int row0 = ob * 32 + mt * 16 + quad * 4;   // o
#pragma unroll
        for (int nt = 0; nt < 4; nt++) {
            int g = mt * 4 + nt;
            f32x4 other = *(const f32x4*)(&Ocomb[lane][(g ^ csw) * 4]);
            int col = sb * 64 + nt * 16 + l15;     // s
#pragma unroll
            for (int r = 0; r < 4; r++)
                out[((size_t)n * kDV + row0 + r) * kS + col] =
                    acc[mt][nt][r] + other[r] + bias[row0 + r];
        }
    }
}

// ---------------------------------------------------------------------------
extern "C" void kernel_launch(void* const* d_in, const int* in_sizes, int n_in,
                              void* d_out, int out_size, void* d_ws, size_t ws_size,
                              hipStream_t stream) {
    const float* x      = (const float*)d_in[0];
    const float* w_qkv  = (const float*)d_in[1];
    const float* b_qkv  = (const float*)d_in[2];
    const float* w_proj = (const float*)d_in[3];
    const float* b_proj = (const float*)d_in[4];
    float* out = (float*)d_out;

    constexpr size_t kXE = (size_t)kN * kS * kC;     // 2,359,296
    unsigned short* wh = (unsigned short*)d_ws;      // w_qkv B-frag f16-hi
    unsigned short* wl = wh + 196608;                // w_qkv B-frag f16-lo
    f16* wpF   = (f16*)(wl + 196608);                // w_proj A-frag f16
    f16* Qf    = wpF + 65536;                        // [32 nh][2304][32]
    f16* Kf    = Qf + kXE;
    f16* Vp    = Kf + kXE;                           // [32 nh][144][64][8] scrambled A-frag
    f16* attnF = Vp + kXE;                           // B-frag [n][144][8][512]

    prep_w<<<dim3(128), 256, 0, stream>>>(w_qkv, w_proj, wh, wl, wpF);

    gemm_qkv<<<dim3(36, 3, 4), 512, 0, stream>>>(x, wh, wl, b_qkv, Qf, Kf, Vp);

    attn_f16<<<dim3(8, 36, 4), 192, 0, stream>>>(Qf, Kf, Vp, attnF);

    gemm_out<<<dim3(8, 36, 4), 128, 0, stream>>>(wpF, attnF, b_proj, out);
}